// Round 14
// baseline (650.182 us; speedup 1.0000x reference)
//
#include <hip/hip_runtime.h>
#include <hip/hip_bf16.h>
#include <stdint.h>
#include <stddef.h>

#ifndef PARTITIONABLE
#define PARTITIONABLE 1
#endif

typedef __attribute__((ext_vector_type(8))) short short8;
typedef __attribute__((ext_vector_type(4))) short short4v;
typedef __attribute__((ext_vector_type(4))) float f32x4;

// ---------------- threefry2x32 (exact JAX) ----------------
__host__ __device__ __forceinline__ uint32_t rotl32(uint32_t x, int d){ return (x<<d)|(x>>(32-d)); }

__host__ __device__ __forceinline__ void tf4(uint32_t&x0, uint32_t&x1, int r0,int r1,int r2,int r3){
  x0+=x1; x1=rotl32(x1,r0); x1^=x0;
  x0+=x1; x1=rotl32(x1,r1); x1^=x0;
  x0+=x1; x1=rotl32(x1,r2); x1^=x0;
  x0+=x1; x1=rotl32(x1,r3); x1^=x0;
}
__host__ __device__ __forceinline__ void threefry2x32(uint32_t k0,uint32_t k1,uint32_t x0,uint32_t x1,
                                                      uint32_t&y0,uint32_t&y1){
  uint32_t ks2 = k0^k1^0x1BD11BDAu;
  x0+=k0; x1+=k1;
  tf4(x0,x1,13,15,26,6);  x0+=k1;  x1+=ks2+1u;
  tf4(x0,x1,17,29,16,24); x0+=ks2; x1+=k0+2u;
  tf4(x0,x1,13,15,26,6);  x0+=k0;  x1+=k1+3u;
  tf4(x0,x1,17,29,16,24); x0+=k1;  x1+=ks2+4u;
  tf4(x0,x1,13,15,26,6);  x0+=ks2; x1+=k0+5u;
  y0=x0; y1=x1;
}

__device__ __forceinline__ uint32_t random_bits32(uint32_t k0,uint32_t k1,uint32_t idx, uint32_t half){
#if PARTITIONABLE
  uint32_t y0,y1; threefry2x32(k0,k1, 0u, idx, y0,y1);
  (void)half;
  return y0 ^ y1;
#else
  uint32_t y0,y1;
  if (idx < half) { threefry2x32(k0,k1, idx, idx+half, y0,y1); return y0; }
  else            { threefry2x32(k0,k1, idx-half, idx, y0,y1); return y1; }
#endif
}

// ---------------- bf16 split helpers ----------------
__device__ __forceinline__ unsigned short bf16_rne(float x){
  unsigned u = __float_as_uint(x);
  unsigned r = (u + 0x7FFFu + ((u>>16)&1u)) >> 16;
  return (unsigned short)r;
}
__device__ __forceinline__ float bf16_tof(unsigned short h){
  return __uint_as_float(((unsigned)h)<<16);
}
__device__ __forceinline__ void split8(const float* src, short8& hi, short8& lo){
  #pragma unroll
  for (int e=0;e<8;e++){
    unsigned short h = bf16_rne(src[e]);
    hi[e] = (short)h;
    lo[e] = (short)bf16_rne(src[e] - bf16_tof(h));
  }
}
__device__ __forceinline__ void split4(const float* src, short4v& hi, short4v& lo){
  #pragma unroll
  for (int e=0;e<4;e++){
    unsigned short h = bf16_rne(src[e]);
    hi[e] = (short)h;
    lo[e] = (short)bf16_rne(src[e] - bf16_tof(h));
  }
}

// ---------------- async global->LDS (16B/lane) ----------------
__device__ __forceinline__ void gll16(const void* g, void* l){
  __builtin_amdgcn_global_load_lds(
      (const __attribute__((address_space(1))) unsigned int*)g,
      (__attribute__((address_space(3))) unsigned int*)l, 16, 0, 0);
}

// ---------------- Markidis split-2 core (bit-frozen vs rounds 4-13) ----------------
__device__ __forceinline__ void mk1_gemm(const float* __restrict__ A, int lda,
                                         const unsigned short* __restrict__ packB,
                                         int K, char* smem, f32x4 (&acc)[2][4]){
  const int tid=threadIdx.x, lane=tid&63, wv=tid>>6;
  const int wr=wv>>2, wc=wv&3;
  const int arow=tid>>3, aseg=tid&7, swA=(arow>>1)&3;
  unsigned short* Ahi=(unsigned short*)smem;
  unsigned short* Alo=(unsigned short*)(smem+4096);
  unsigned short* Bhi=(unsigned short*)(smem+8192);
  unsigned short* Blo=(unsigned short*)(smem+24576);
  const int NT=K/32;
  const int sA = arow*32 + ((aseg>>1)^swA)*8 + (aseg&1)*4;
  const int seg = wv*2;

  float4 av = *(const float4*)(A + (size_t)arow*lda + aseg*4);
  for(int t=0;t<NT;t++){
    __syncthreads();
    {
      float af[4]={av.x,av.y,av.z,av.w}; short4v vh,vl; split4(af,vh,vl);
      *(short4v*)&Ahi[sA]=vh; *(short4v*)&Alo[sA]=vl;
      const unsigned short* src = packB + (size_t)t*16384;
      #pragma unroll
      for(int q=0;q<2;q++){
        gll16(src + (seg+q)*512 + lane*8,        (char*)Bhi + (seg+q)*1024);
        gll16(src + 8192 + (seg+q)*512 + lane*8, (char*)Blo + (seg+q)*1024);
      }
      if (t+1<NT) av = *(const float4*)(A + (size_t)arow*lda + (t+1)*32 + aseg*4);
    }
    __syncthreads();
    short8 ah[2],al[2],bh[4],bl[4];
    const int kg=lane>>4;
    #pragma unroll
    for(int i=0;i<2;i++){
      const int r = wr*32 + i*16 + (lane&15);
      const int offA = r*32 + ((kg ^ ((r>>1)&3))*8);
      ah[i]=*(const short8*)&Ahi[offA]; al[i]=*(const short8*)&Alo[offA];
    }
    #pragma unroll
    for(int j=0;j<4;j++){
      const int c = wc*64 + j*16 + (lane&15);
      const int offB = c*32 + ((kg ^ ((c>>1)&3))*8);
      bh[j]=*(const short8*)&Bhi[offB]; bl[j]=*(const short8*)&Blo[offB];
    }
    #pragma unroll
    for(int i=0;i<2;i++)
      #pragma unroll
      for(int j=0;j<4;j++){
        acc[i][j]=__builtin_amdgcn_mfma_f32_16x16x32_bf16(ah[i],bh[j],acc[i][j],0,0,0);
        acc[i][j]=__builtin_amdgcn_mfma_f32_16x16x32_bf16(ah[i],bl[j],acc[i][j],0,0,0);
        acc[i][j]=__builtin_amdgcn_mfma_f32_16x16x32_bf16(al[i],bh[j],acc[i][j],0,0,0);
      }
  }
}

// ---------------- BN(+ReLU) 4-col, transposed store (validated R9-R13) ----------------
__device__ __forceinline__ void bn_block_t(float (&acc)[4], int col0,
                                           const float* __restrict__ gma,
                                           const float* __restrict__ bta,
                                           float* __restrict__ Yt,
                                           float* Zs, float* red, float* mcol, float* vcol){
  const int r = threadIdx.x;
  #pragma unroll
  for (int j=0;j<4;j++) Zs[r*5+j] = acc[j];
  __syncthreads();
  if (r < 16){
    const int rl = r & 3, j = r >> 2;
    float s = 0.f;
    for (int rr=rl; rr<256; rr+=4) s += Zs[rr*5+j];
    red[rl*4+j] = s;
  }
  __syncthreads();
  if (r < 4)
    mcol[r] = (red[0*4+r]+red[1*4+r]+red[2*4+r]+red[3*4+r]) * (1.0f/256.0f);
  __syncthreads();
  if (r < 16){
    const int rl = r & 3, j = r >> 2;
    const float m = mcol[j];
    float s2 = 0.f;
    for (int rr=rl; rr<256; rr+=4){ float d = Zs[rr*5+j]-m; s2 += d*d; }
    red[rl*4+j] = s2;
  }
  __syncthreads();
  if (r < 4)
    vcol[r] = (red[0*4+r]+red[1*4+r]+red[2*4+r]+red[3*4+r]) * (1.0f/256.0f);
  __syncthreads();
  #pragma unroll
  for (int j=0;j<4;j++){
    const int c = col0 + j;
    const float scale = gma[c] * rsqrtf(vcol[j] + 1e-5f);
    const float sh = bta[c];
    const float v = (acc[j]-mcol[j])*scale + sh;
    Yt[(size_t)c*256 + r] = v > 0.f ? v : 0.f;
  }
}

// ---------------- prep: pack proj_w (job b) + l0 BN (job b) — R13 stage0a/0b bodies (validated) ----------------
__global__ __launch_bounds__(256) void prep_kernel(
    const float* __restrict__ proj_w, unsigned short* __restrict__ packW,
    const float* __restrict__ w0, const float* __restrict__ b0,
    const float* __restrict__ g0, const float* __restrict__ be0,
    float* __restrict__ XtA){
  __shared__ float Zs[256*5];
  __shared__ float red[16], mcol[4], vcol[4];
  const int b = blockIdx.x, tid = threadIdx.x;
  {
    const int t = b>>2, s = b&3, c = tid;
    const int g = s ^ ((c>>1)&3);
    const float* p = proj_w + (size_t)(t*32 + g*8)*256 + c;
    float bf[8];
    #pragma unroll
    for(int e=0;e<8;e++) bf[e]=p[(size_t)e*256];
    short8 h,l; split8(bf,h,l);
    unsigned short* dst = packW + (size_t)t*16384 + c*32 + s*8;
    *(short8*)dst = h;
    *(short8*)(dst+8192) = l;
  }
  {
    const int col0 = b*4;
    float acc[4];
    #pragma unroll
    for (int j=0;j<4;j++) acc[j] = b0[col0+j];
    #pragma unroll
    for (int jj=0;jj<8;jj++){
      if ((tid >> (7-jj)) & 1){
        #pragma unroll
        for (int j=0;j<4;j++) acc[j] += w0[jj*1024 + col0 + j];
      }
    }
    bn_block_t(acc, col0, g0, be0, XtA, Zs, red, mcol, vcol);
  }
}

// ---------------- mid layer: 64 blocks x 16 cols — read-amplification fix ----------------
// Block stages its 64KB W panel in LDS (broadcast k-loop reads are conflict-free);
// each block streams Xt once (64 MB total/layer vs R12's 512 MB). Per-(r,c): single
// accumulator, k ascending -> bits identical. BN = exact stripe-order replica (16 cols).
__global__ __launch_bounds__(256) void mid16_kernel(
    const float* __restrict__ Xt, const float* __restrict__ W,
    const float* __restrict__ bias,
    const float* __restrict__ gma, const float* __restrict__ bta,
    float* __restrict__ Yt){
  __shared__ float Ws[1024*16];      // 64 KB
  __shared__ float Zs[256*17];       // 17408 B
  __shared__ float red[64], mcol[16], vcol[16];
  const int r = threadIdx.x;
  const int c0 = blockIdx.x*16;
  #pragma unroll
  for (int idx = r; idx < 4096; idx += 256){
    const int row = idx>>2, seg = idx&3;
    *(float4*)&Ws[row*16 + seg*4] = *(const float4*)&W[(size_t)row*1024 + c0 + seg*4];
  }
  __syncthreads();
  float acc[16];
  #pragma unroll
  for (int j=0;j<16;j++) acc[j]=0.f;
  #pragma unroll 8
  for (int k=0;k<1024;k++){
    const float a = Xt[(size_t)k*256 + r];
    #pragma unroll
    for (int j=0;j<16;j++) acc[j] += a*Ws[k*16+j];
  }
  #pragma unroll
  for (int j=0;j<16;j++) acc[j] += bias[c0+j];
  // BN: per-col stats, 4 serial stripes ascending + left-assoc combine (exact replica)
  #pragma unroll
  for (int j=0;j<16;j++) Zs[r*17+j] = acc[j];
  __syncthreads();
  if (r < 64){
    const int rl = r & 3, j = r >> 2;
    float s=0.f;
    for (int rr=rl; rr<256; rr+=4) s += Zs[rr*17+j];
    red[rl*16+j] = s;
  }
  __syncthreads();
  if (r < 16) mcol[r] = (red[0*16+r]+red[1*16+r]+red[2*16+r]+red[3*16+r])*(1.0f/256.0f);
  __syncthreads();
  if (r < 64){
    const int rl = r & 3, j = r >> 2;
    const float m = mcol[j];
    float s2=0.f;
    for (int rr=rl; rr<256; rr+=4){ float d=Zs[rr*17+j]-m; s2+=d*d; }
    red[rl*16+j] = s2;
  }
  __syncthreads();
  if (r < 16) vcol[r] = (red[0*16+r]+red[1*16+r]+red[2*16+r]+red[3*16+r])*(1.0f/256.0f);
  __syncthreads();
  #pragma unroll
  for (int j=0;j<16;j++){
    const int c = c0+j;
    const float scale = gma[c]*rsqrtf(vcol[j]+1e-5f);
    const float v = (acc[j]-mcol[j])*scale + bta[c];
    Yt[(size_t)c*256 + r] = v>0.f ? v : 0.f;
  }
}

// ---------------- tail: wL GEMM + rownorm + packE + Epp (R12 body, bit-frozen) ----------------
__global__ __launch_bounds__(256) void mlp_tail_kernel(
    const float* __restrict__ Xt,
    const float* __restrict__ wL, const float* __restrict__ bL,
    const float* __restrict__ pinv_w, const float* __restrict__ pinv_b,
    float* __restrict__ embed, unsigned short* __restrict__ packE,
    float* __restrict__ Epp){
  __shared__ float xrow[1024];
  __shared__ float erow[256];
  __shared__ float wsum[4];
  const int n = blockIdx.x, t = threadIdx.x;
  #pragma unroll
  for (int q=0;q<4;q++) xrow[q*256+t] = Xt[(size_t)(q*256+t)*256 + n];
  __syncthreads();
  float acc = 0.f;
  #pragma unroll 16
  for (int k=0;k<1024;k++) acc += xrow[k] * wL[(size_t)k*256 + t];
  acc += bL[t];
  const int lane = t & 63, wv = t >> 6;
  float v = acc*acc;
  #pragma unroll
  for (int o=32;o;o>>=1) v += __shfl_xor(v,o);
  if (lane==0) wsum[wv]=v;
  __syncthreads();
  const float total = wsum[0]+wsum[1]+wsum[2]+wsum[3];
  const float inv = 1.0f/(sqrtf(total)+1e-6f);
  const float y = acc*inv;
  embed[(size_t)n*256+t] = y;
  erow[t] = y;
  {
    unsigned short h = bf16_rne(y);
    unsigned short l = bf16_rne(y - bf16_tof(h));
    const int tt=t>>5, kk=t&31, g=kk>>3, e=kk&7, s=g^((n>>1)&3);
    unsigned short* d = packE + (size_t)tt*16384 + n*32 + s*8 + e;
    d[0] = h; d[8192] = l;
  }
  __syncthreads();
  float a8[8] = {0.f,0.f,0.f,0.f,0.f,0.f,0.f,0.f};
  #pragma unroll 8
  for (int k=0;k<256;k++){
    const float ev = erow[k];
    const float4 w0v = *(const float4*)&pinv_w[(size_t)k*2048 + t*8];
    const float4 w1v = *(const float4*)&pinv_w[(size_t)k*2048 + t*8 + 4];
    a8[0] += ev*w0v.x; a8[1] += ev*w0v.y; a8[2] += ev*w0v.z; a8[3] += ev*w0v.w;
    a8[4] += ev*w1v.x; a8[5] += ev*w1v.y; a8[6] += ev*w1v.z; a8[7] += ev*w1v.w;
  }
  #pragma unroll
  for (int j=0;j<8;j++) a8[j] += pinv_b[t*8+j];
  float4* dst = (float4*)(Epp + (size_t)n*2048 + t*8);
  dst[0] = (float4){a8[0],a8[1],a8[2],a8[3]};
  dst[1] = (float4){a8[4],a8[5],a8[6],a8[7]};
}

// ---------------- proj + rownorm fused (bit-frozen) ----------------
__global__ __launch_bounds__(512) void proj_norm_kernel(
    const float* __restrict__ A, const unsigned short* __restrict__ packW,
    const float* __restrict__ bias, float* __restrict__ Hn, int K){
  __shared__ char smem[40960];
  f32x4 acc[2][4];
  #pragma unroll
  for (int i=0;i<2;i++)
    #pragma unroll
    for (int j=0;j<4;j++) acc[i][j] = (f32x4){0.f,0.f,0.f,0.f};
  const int bm = blockIdx.x * 64;
  mk1_gemm(A + (size_t)bm*K, K, packW, K, smem, acc);
  __syncthreads();

  const int tid = threadIdx.x, lane = tid&63, wv = tid>>6;
  const int wr = wv>>2, wc = wv&3;
  float* ns = (float*)smem;
  #pragma unroll
  for (int j=0;j<4;j++){
    const int c = wc*64 + j*16 + (lane&15);
    const float bb = bias[c];
    #pragma unroll
    for (int i=0;i<2;i++)
      #pragma unroll
      for (int reg=0;reg<4;reg++) acc[i][j][reg] += bb;
  }
  #pragma unroll
  for (int i=0;i<2;i++)
    #pragma unroll
    for (int reg=0;reg<4;reg++){
      float p = acc[i][0][reg]*acc[i][0][reg] + acc[i][1][reg]*acc[i][1][reg]
              + acc[i][2][reg]*acc[i][2][reg] + acc[i][3][reg]*acc[i][3][reg];
      #pragma unroll
      for (int o=1;o<16;o<<=1) p += __shfl_xor(p, o);
      if ((lane&15)==0) ns[wc*64 + wr*32 + i*16 + (lane>>4)*4 + reg] = p;
    }
  __syncthreads();
  #pragma unroll
  for (int i=0;i<2;i++){
    const int rl = wr*32 + i*16 + (lane>>4)*4;
    #pragma unroll
    for (int reg=0;reg<4;reg++){
      const int r = rl + reg;
      const float tot = ns[0*64+r]+ns[1*64+r]+ns[2*64+r]+ns[3*64+r];
      const float inv = 1.0f/(sqrtf(tot)+1e-6f);
      const size_t grow = (size_t)(bm + r);
      #pragma unroll
      for (int j=0;j<4;j++){
        const int c = wc*64 + j*16 + (lane&15);
        Hn[grow*256 + c] = acc[i][j][reg]*inv;
      }
    }
  }
}

// ---------------- sim GEMM + softmax + gumbel-argmax + outputs + q_inv, fused (bit-frozen) ----------------
__global__ __launch_bounds__(512) void sim_sample_kernel(
    const float* __restrict__ Hn, const unsigned short* __restrict__ packE,
    const float* __restrict__ embed, const float* __restrict__ temp,
    float* __restrict__ probs, float* __restrict__ codef,
    float* __restrict__ quant, float* __restrict__ norms,
    const float* __restrict__ Epp, const float* __restrict__ pinv_b,
    float* __restrict__ q_inv,
    uint32_t kc0, uint32_t kc1, uint32_t kp0, uint32_t kp1){
  __shared__ char smem[40960];
  f32x4 acc[2][4];
  #pragma unroll
  for (int i=0;i<2;i++)
    #pragma unroll
    for (int j=0;j<4;j++) acc[i][j] = (f32x4){0.f,0.f,0.f,0.f};
  const int bm = blockIdx.x * 64;
  mk1_gemm(Hn + (size_t)bm*256, 256, packE, 256, smem, acc);
  __syncthreads();

  float* redf = (float*)smem;            // [4][64]
  int*   redi = (int*)(smem+1024);       // [4][64]
  float* smax = (float*)(smem+2048);     // [64]
  float* ssum = (float*)(smem+2304);     // [64]
  float* ssel = (float*)(smem+2560);     // [64]
  int*  scode = (int*)(smem+2816);       // [64]

  const int tid = threadIdx.x, lane = tid&63, wv = tid>>6;
  const int wr = wv>>2, wc = wv&3;
  const float tv = temp[0];
  const float alpha = 1.0f/(tv*tv);
  #pragma unroll
  for (int i=0;i<2;i++)
    #pragma unroll
    for (int j=0;j<4;j++)
      #pragma unroll
      for (int reg=0;reg<4;reg++){
        const float s = acc[i][j][reg];
        const float dist = -2.0f*(alpha-1.0f)*s - 2.0f*s;
        acc[i][j][reg] = -dist;
      }
  // row max
  #pragma unroll
  for (int i=0;i<2;i++)
    #pragma unroll
    for (int reg=0;reg<4;reg++){
      float m = fmaxf(fmaxf(acc[i][0][reg], acc[i][1][reg]),
                      fmaxf(acc[i][2][reg], acc[i][3][reg]));
      #pragma unroll
      for (int o=1;o<16;o<<=1) m = fmaxf(m, __shfl_xor(m, o));
      if ((lane&15)==0) redf[wc*64 + wr*32 + i*16 + (lane>>4)*4 + reg] = m;
    }
  __syncthreads();
  if (tid < 64)
    smax[tid] = fmaxf(fmaxf(redf[0*64+tid], redf[1*64+tid]), fmaxf(redf[2*64+tid], redf[3*64+tid]));
  __syncthreads();
  // exp-sum
  #pragma unroll
  for (int i=0;i<2;i++)
    #pragma unroll
    for (int reg=0;reg<4;reg++){
      const int r = wr*32 + i*16 + (lane>>4)*4 + reg;
      const float m = smax[r];
      float p = expf(acc[i][0][reg]-m) + expf(acc[i][1][reg]-m)
              + expf(acc[i][2][reg]-m) + expf(acc[i][3][reg]-m);
      #pragma unroll
      for (int o=1;o<16;o<<=1) p += __shfl_xor(p, o);
      if ((lane&15)==0) redf[wc*64 + r] = p;
    }
  __syncthreads();
  if (tid < 64){
    ssum[tid] = redf[0*64+tid]+redf[1*64+tid]+redf[2*64+tid]+redf[3*64+tid];
    const uint32_t pb = random_bits32(kp0,kp1,(uint32_t)(bm+tid), 16384u);
    const float pf = __uint_as_float((pb>>9) | 0x3f800000u) - 1.0f;
    ssel[tid] = (pf > 0.0f) ? 1.0f : 0.0f;
  }
  __syncthreads();
  // gumbel argmax (bit-frozen comparison order)
  #pragma unroll
  for (int i=0;i<2;i++)
    #pragma unroll
    for (int reg=0;reg<4;reg++){
      const int r = wr*32 + i*16 + (lane>>4)*4 + reg;
      const uint32_t grow = (uint32_t)(bm + r);
      float zb = -1e38f; int ib = 0x7fffffff;
      #pragma unroll
      for (int j=0;j<4;j++){
        const int c = wc*64 + j*16 + (lane&15);
        const uint32_t bits = random_bits32(kc0,kc1, grow*256u + (uint32_t)c, 4194304u);
        const float f = __uint_as_float((bits>>9) | 0x3f800000u) - 1.0f;
        const float TINY = 1.17549435082228751e-38f;
        const float u = fmaxf(TINY, f + TINY);
        const float g = -logf(-logf(u));
        const float z = acc[i][j][reg] + g;
        if (z > zb || (z == zb && c < ib)){ zb = z; ib = c; }
      }
      #pragma unroll
      for (int o=1;o<16;o<<=1){
        const float zo = __shfl_xor(zb, o); const int io = __shfl_xor(ib, o);
        if (zo > zb || (zo == zb && io < ib)){ zb = zo; ib = io; }
      }
      if ((lane&15)==0){ redf[wc*64 + r] = zb; redi[wc*64 + r] = ib; }
    }
  __syncthreads();
  if (tid < 64){
    float zb = redf[0*64+tid]; int ib = redi[0*64+tid];
    #pragma unroll
    for (int w=1; w<4; w++)
      if (redf[w*64+tid] > zb || (redf[w*64+tid] == zb && redi[w*64+tid] < ib)){
        zb = redf[w*64+tid]; ib = redi[w*64+tid];
      }
    scode[tid] = ib;
  }
  __syncthreads();
  // probs/quant + ||embed[code]-h|| partials
  #pragma unroll
  for (int i=0;i<2;i++)
    #pragma unroll
    for (int reg=0;reg<4;reg++){
      const int r = wr*32 + i*16 + (lane>>4)*4 + reg;
      const size_t grow = (size_t)(bm + r);
      const float m = smax[r], sum = ssum[r], sel = ssel[r];
      const int code = scode[r];
      float p2 = 0.f;
      #pragma unroll
      for (int j=0;j<4;j++){
        const int c = wc*64 + j*16 + (lane&15);
        const float e = expf(acc[i][j][reg] - m);
        probs[grow*256 + c] = (e/sum) * sel;
        const float ev = embed[(size_t)code*256 + c];
        quant[grow*256 + c] = ev * sel;
        const float d = ev - Hn[grow*256 + c];
        p2 += d*d;
      }
      #pragma unroll
      for (int o=1;o<16;o<<=1) p2 += __shfl_xor(p2, o);
      if ((lane&15)==0) redf[wc*64 + r] = p2;
    }
  __syncthreads();
  if (tid < 64){
    norms[bm+tid] = sqrtf(redf[0*64+tid]+redf[1*64+tid]+redf[2*64+tid]+redf[3*64+tid]);
    codef[bm+tid] = (float)scode[tid] * ssel[tid];
  }
  // q_inv rows: sel ? Epp[code] : pinv_b
  #pragma unroll
  for (int rr=0; rr<8; rr++){
    const int r = wv*8 + rr;
    const int code = scode[r];
    const float sel = ssel[r];
    const float4* s4 = (const float4*)((sel != 0.0f) ? (Epp + (size_t)code*2048) : pinv_b);
    float4* dst = (float4*)(q_inv + (size_t)(bm + r)*2048);
    #pragma unroll
    for (int q=0;q<8;q++) dst[q*64 + lane] = s4[q*64 + lane];
  }
}

// ---------------- vq_loss = mean(norms) ----------------
__global__ __launch_bounds__(256) void loss_kernel(const float* __restrict__ norms,
                                                   float* __restrict__ outp){
  const int t = threadIdx.x;
  float s = 0.f;
  for (int i=t;i<32768;i+=256) s += norms[i];
  #pragma unroll
  for (int o=32;o;o>>=1) s += __shfl_xor(s,o);
  __shared__ float wred[4];
  if ((t&63)==0) wred[t>>6]=s;
  __syncthreads();
  if (t==0) outp[0] = (wred[0]+wred[1]+wred[2]+wred[3]) * (1.0f/32768.0f);
}

// ---------------- launch ----------------
extern "C" void kernel_launch(void* const* d_in, const int* in_sizes, int n_in,
                              void* d_out, int out_size, void* d_ws, size_t ws_size,
                              hipStream_t stream){
  const float* h_in  = (const float*)d_in[0];
  const float* temp  = (const float*)d_in[1];
  const float* proj_w= (const float*)d_in[2];
  const float* proj_b= (const float*)d_in[3];
  const float* pinv_w= (const float*)d_in[4];
  const float* pinv_b= (const float*)d_in[5];
  const float* w0 = (const float*)d_in[6];
  const float* b0 = (const float*)d_in[7];
  const float* g0 = (const float*)d_in[8];
  const float* be0= (const float*)d_in[9];
  const float* wm = (const float*)d_in[10];
  const float* bm = (const float*)d_in[11];
  const float* gm = (const float*)d_in[12];
  const float* bem= (const float*)d_in[13];
  const float* wL = (const float*)d_in[14];
  const float* bL = (const float*)d_in[15];

  float* out = (float*)d_out;
  float* q_inv  = out;                  // [32768,2048]
  float* o_code = out + 67108864;       // [32768]
  float* o_quant= out + 67141632;       // [32768,256]
  float* o_probs= out + 75530240;       // [32768,256]
  float* o_loss = out + 83918848;       // [1]

  // scratch in d_ws
  float* ws = (float*)d_ws;
  float* Hn     = ws + 0;               // [32768,256]
  float* XtA    = ws + 8388608;         // [1024,256] transposed activations
  float* XtB    = ws + 8650752;         // [1024,256]
  float* embed  = ws + 8912896;         // [256,256]
  float* norms  = ws + 8978432;         // [32768]
  float* Epp    = ws + 9076736;         // [256,2048]
  unsigned short* packW = (unsigned short*)(ws + 9601024);   // 64 steps x 16384 shorts
  unsigned short* packE = (unsigned short*)(ws + 10125312);  // 8 steps x 16384 shorts

  uint32_t kc0,kc1,kp0,kp1;
#if PARTITIONABLE
  threefry2x32(0u,42u, 0u,0u, kc0,kc1);
  threefry2x32(0u,42u, 0u,1u, kp0,kp1);
#else
  { uint32_t a0,b0w,a1,b1w;
    threefry2x32(0u,42u, 0u,2u, a0,b0w);
    threefry2x32(0u,42u, 1u,3u, a1,b1w);
    kc0=a0; kc1=a1; kp0=b0w; kp1=b1w; }
#endif

  // pack proj_w + l0 (one launch; independent jobs, validated bodies)
  prep_kernel<<<256,256,0,stream>>>(proj_w, packW, w0, b0, g0, be0, XtA);

  // big proj (depends only on packW)
  proj_norm_kernel<<<512,512,0,stream>>>(h_in, packW, proj_b, Hn, 2048);

  // codebook MLP mids: 64 blocks x 16 cols (read-amplification fix), bits identical
  mid16_kernel<<<64,256,0,stream>>>(XtA, wm + 0*1048576, bm + 0*1024, gm + 0*1024, bem + 0*1024, XtB);
  mid16_kernel<<<64,256,0,stream>>>(XtB, wm + 1*1048576, bm + 1*1024, gm + 1*1024, bem + 1*1024, XtA);
  mid16_kernel<<<64,256,0,stream>>>(XtA, wm + 2*1048576, bm + 2*1024, gm + 2*1024, bem + 2*1024, XtB);
  mid16_kernel<<<64,256,0,stream>>>(XtB, wm + 3*1048576, bm + 3*1024, gm + 3*1024, bem + 3*1024, XtA);
  mlp_tail_kernel<<<256,256,0,stream>>>(XtA, wL, bL, pinv_w, pinv_b, embed, packE, Epp);

  // sim + sample + all per-token outputs incl. q_inv
  sim_sample_kernel<<<512,512,0,stream>>>(Hn, packE, embed, temp,
                                          o_probs, o_code, o_quant, norms,
                                          Epp, pinv_b, q_inv,
                                          kc0,kc1,kp0,kp1);
  loss_kernel<<<1,256,0,stream>>>(norms, o_loss);
}

// Round 15
// 571.168 us; speedup vs baseline: 1.1383x; 1.1383x over previous
//
#include <hip/hip_runtime.h>
#include <hip/hip_bf16.h>
#include <stdint.h>
#include <stddef.h>

#ifndef PARTITIONABLE
#define PARTITIONABLE 1
#endif

typedef __attribute__((ext_vector_type(8))) short short8;
typedef __attribute__((ext_vector_type(4))) short short4v;
typedef __attribute__((ext_vector_type(4))) float f32x4;

// ---------------- threefry2x32 (exact JAX) ----------------
__host__ __device__ __forceinline__ uint32_t rotl32(uint32_t x, int d){ return (x<<d)|(x>>(32-d)); }

__host__ __device__ __forceinline__ void tf4(uint32_t&x0, uint32_t&x1, int r0,int r1,int r2,int r3){
  x0+=x1; x1=rotl32(x1,r0); x1^=x0;
  x0+=x1; x1=rotl32(x1,r1); x1^=x0;
  x0+=x1; x1=rotl32(x1,r2); x1^=x0;
  x0+=x1; x1=rotl32(x1,r3); x1^=x0;
}
__host__ __device__ __forceinline__ void threefry2x32(uint32_t k0,uint32_t k1,uint32_t x0,uint32_t x1,
                                                      uint32_t&y0,uint32_t&y1){
  uint32_t ks2 = k0^k1^0x1BD11BDAu;
  x0+=k0; x1+=k1;
  tf4(x0,x1,13,15,26,6);  x0+=k1;  x1+=ks2+1u;
  tf4(x0,x1,17,29,16,24); x0+=ks2; x1+=k0+2u;
  tf4(x0,x1,13,15,26,6);  x0+=k0;  x1+=k1+3u;
  tf4(x0,x1,17,29,16,24); x0+=k1;  x1+=ks2+4u;
  tf4(x0,x1,13,15,26,6);  x0+=ks2; x1+=k0+5u;
  y0=x0; y1=x1;
}

__device__ __forceinline__ uint32_t random_bits32(uint32_t k0,uint32_t k1,uint32_t idx, uint32_t half){
#if PARTITIONABLE
  uint32_t y0,y1; threefry2x32(k0,k1, 0u, idx, y0,y1);
  (void)half;
  return y0 ^ y1;
#else
  uint32_t y0,y1;
  if (idx < half) { threefry2x32(k0,k1, idx, idx+half, y0,y1); return y0; }
  else            { threefry2x32(k0,k1, idx-half, idx, y0,y1); return y1; }
#endif
}

// ---------------- bf16 split helpers ----------------
__device__ __forceinline__ unsigned short bf16_rne(float x){
  unsigned u = __float_as_uint(x);
  unsigned r = (u + 0x7FFFu + ((u>>16)&1u)) >> 16;
  return (unsigned short)r;
}
__device__ __forceinline__ float bf16_tof(unsigned short h){
  return __uint_as_float(((unsigned)h)<<16);
}
__device__ __forceinline__ void split8(const float* src, short8& hi, short8& lo){
  #pragma unroll
  for (int e=0;e<8;e++){
    unsigned short h = bf16_rne(src[e]);
    hi[e] = (short)h;
    lo[e] = (short)bf16_rne(src[e] - bf16_tof(h));
  }
}
__device__ __forceinline__ void split4(const float* src, short4v& hi, short4v& lo){
  #pragma unroll
  for (int e=0;e<4;e++){
    unsigned short h = bf16_rne(src[e]);
    hi[e] = (short)h;
    lo[e] = (short)bf16_rne(src[e] - bf16_tof(h));
  }
}

// ---------------- async global->LDS (16B/lane) ----------------
__device__ __forceinline__ void gll16(const void* g, void* l){
  __builtin_amdgcn_global_load_lds(
      (const __attribute__((address_space(1))) unsigned int*)g,
      (__attribute__((address_space(3))) unsigned int*)l, 16, 0, 0);
}

// ---------------- Markidis split-2 core (bit-frozen vs rounds 4-14) ----------------
__device__ __forceinline__ void mk1_gemm(const float* __restrict__ A, int lda,
                                         const unsigned short* __restrict__ packB,
                                         int K, char* smem, f32x4 (&acc)[2][4]){
  const int tid=threadIdx.x, lane=tid&63, wv=tid>>6;
  const int wr=wv>>2, wc=wv&3;
  const int arow=tid>>3, aseg=tid&7, swA=(arow>>1)&3;
  unsigned short* Ahi=(unsigned short*)smem;
  unsigned short* Alo=(unsigned short*)(smem+4096);
  unsigned short* Bhi=(unsigned short*)(smem+8192);
  unsigned short* Blo=(unsigned short*)(smem+24576);
  const int NT=K/32;
  const int sA = arow*32 + ((aseg>>1)^swA)*8 + (aseg&1)*4;
  const int seg = wv*2;

  float4 av = *(const float4*)(A + (size_t)arow*lda + aseg*4);
  for(int t=0;t<NT;t++){
    __syncthreads();
    {
      float af[4]={av.x,av.y,av.z,av.w}; short4v vh,vl; split4(af,vh,vl);
      *(short4v*)&Ahi[sA]=vh; *(short4v*)&Alo[sA]=vl;
      const unsigned short* src = packB + (size_t)t*16384;
      #pragma unroll
      for(int q=0;q<2;q++){
        gll16(src + (seg+q)*512 + lane*8,        (char*)Bhi + (seg+q)*1024);
        gll16(src + 8192 + (seg+q)*512 + lane*8, (char*)Blo + (seg+q)*1024);
      }
      if (t+1<NT) av = *(const float4*)(A + (size_t)arow*lda + (t+1)*32 + aseg*4);
    }
    __syncthreads();
    short8 ah[2],al[2],bh[4],bl[4];
    const int kg=lane>>4;
    #pragma unroll
    for(int i=0;i<2;i++){
      const int r = wr*32 + i*16 + (lane&15);
      const int offA = r*32 + ((kg ^ ((r>>1)&3))*8);
      ah[i]=*(const short8*)&Ahi[offA]; al[i]=*(const short8*)&Alo[offA];
    }
    #pragma unroll
    for(int j=0;j<4;j++){
      const int c = wc*64 + j*16 + (lane&15);
      const int offB = c*32 + ((kg ^ ((c>>1)&3))*8);
      bh[j]=*(const short8*)&Bhi[offB]; bl[j]=*(const short8*)&Blo[offB];
    }
    #pragma unroll
    for(int i=0;i<2;i++)
      #pragma unroll
      for(int j=0;j<4;j++){
        acc[i][j]=__builtin_amdgcn_mfma_f32_16x16x32_bf16(ah[i],bh[j],acc[i][j],0,0,0);
        acc[i][j]=__builtin_amdgcn_mfma_f32_16x16x32_bf16(ah[i],bl[j],acc[i][j],0,0,0);
        acc[i][j]=__builtin_amdgcn_mfma_f32_16x16x32_bf16(al[i],bh[j],acc[i][j],0,0,0);
      }
  }
}

// ---------------- BN(+ReLU) 4-col, transposed store (validated R9-R14) ----------------
__device__ __forceinline__ void bn_block_t(float (&acc)[4], int col0,
                                           const float* __restrict__ gma,
                                           const float* __restrict__ bta,
                                           float* __restrict__ Yt,
                                           float* Zs, float* red, float* mcol, float* vcol){
  const int r = threadIdx.x;
  #pragma unroll
  for (int j=0;j<4;j++) Zs[r*5+j] = acc[j];
  __syncthreads();
  if (r < 16){
    const int rl = r & 3, j = r >> 2;
    float s = 0.f;
    for (int rr=rl; rr<256; rr+=4) s += Zs[rr*5+j];
    red[rl*4+j] = s;
  }
  __syncthreads();
  if (r < 4)
    mcol[r] = (red[0*4+r]+red[1*4+r]+red[2*4+r]+red[3*4+r]) * (1.0f/256.0f);
  __syncthreads();
  if (r < 16){
    const int rl = r & 3, j = r >> 2;
    const float m = mcol[j];
    float s2 = 0.f;
    for (int rr=rl; rr<256; rr+=4){ float d = Zs[rr*5+j]-m; s2 += d*d; }
    red[rl*4+j] = s2;
  }
  __syncthreads();
  if (r < 4)
    vcol[r] = (red[0*4+r]+red[1*4+r]+red[2*4+r]+red[3*4+r]) * (1.0f/256.0f);
  __syncthreads();
  #pragma unroll
  for (int j=0;j<4;j++){
    const int c = col0 + j;
    const float scale = gma[c] * rsqrtf(vcol[j] + 1e-5f);
    const float sh = bta[c];
    const float v = (acc[j]-mcol[j])*scale + sh;
    Yt[(size_t)c*256 + r] = v > 0.f ? v : 0.f;
  }
}

// ---------------- prep: pack proj_w + l0 BN (validated R14) ----------------
__global__ __launch_bounds__(256) void prep_kernel(
    const float* __restrict__ proj_w, unsigned short* __restrict__ packW,
    const float* __restrict__ w0, const float* __restrict__ b0,
    const float* __restrict__ g0, const float* __restrict__ be0,
    float* __restrict__ XtA){
  __shared__ float Zs[256*5];
  __shared__ float red[16], mcol[4], vcol[4];
  const int b = blockIdx.x, tid = threadIdx.x;
  {
    const int t = b>>2, s = b&3, c = tid;
    const int g = s ^ ((c>>1)&3);
    const float* p = proj_w + (size_t)(t*32 + g*8)*256 + c;
    float bf[8];
    #pragma unroll
    for(int e=0;e<8;e++) bf[e]=p[(size_t)e*256];
    short8 h,l; split8(bf,h,l);
    unsigned short* dst = packW + (size_t)t*16384 + c*32 + s*8;
    *(short8*)dst = h;
    *(short8*)(dst+8192) = l;
  }
  {
    const int col0 = b*4;
    float acc[4];
    #pragma unroll
    for (int j=0;j<4;j++) acc[j] = b0[col0+j];
    #pragma unroll
    for (int jj=0;jj<8;jj++){
      if ((tid >> (7-jj)) & 1){
        #pragma unroll
        for (int j=0;j<4;j++) acc[j] += w0[jj*1024 + col0 + j];
      }
    }
    bn_block_t(acc, col0, g0, be0, XtA, Zs, red, mcol, vcol);
  }
}

// ---------------- mid layer: 1-col blocks, grid 1024 (4 blocks/CU, 16 waves/CU) ----------------
// Thread r = row; single acc chain, k ascending — values/order identical to R12's acc0.
// BN = single-column instance of the validated stripe-order replica.
__global__ __launch_bounds__(256) void mid1_kernel(
    const float* __restrict__ Xt, const float* __restrict__ W,
    const float* __restrict__ bias,
    const float* __restrict__ gma, const float* __restrict__ bta,
    float* __restrict__ Yt){
  __shared__ float Ws[1024];
  __shared__ float Zs[256];
  __shared__ float red[4], mcol1[1], vcol1[1];
  const int r = threadIdx.x;
  const int c = blockIdx.x;
  #pragma unroll
  for (int q=0;q<4;q++) Ws[q*256+r] = W[(size_t)(q*256+r)*1024 + c];
  __syncthreads();
  float acc = 0.f;
  #pragma unroll 16
  for (int k=0;k<1024;k++)
    acc += Xt[(size_t)k*256 + r] * Ws[k];
  acc += bias[c];
  // BN stats (exact stripe-order replica, single column)
  Zs[r] = acc;
  __syncthreads();
  if (r < 4){
    float s=0.f;
    for (int rr=r; rr<256; rr+=4) s += Zs[rr];
    red[r] = s;
  }
  __syncthreads();
  if (r == 0) mcol1[0] = (red[0]+red[1]+red[2]+red[3])*(1.0f/256.0f);
  __syncthreads();
  const float m = mcol1[0];
  if (r < 4){
    float s2=0.f;
    for (int rr=r; rr<256; rr+=4){ float d=Zs[rr]-m; s2+=d*d; }
    red[r] = s2;
  }
  __syncthreads();
  if (r == 0) vcol1[0] = (red[0]+red[1]+red[2]+red[3])*(1.0f/256.0f);
  __syncthreads();
  const float scale = gma[c]*rsqrtf(vcol1[0]+1e-5f);
  const float v = (acc-m)*scale + bta[c];
  Yt[(size_t)c*256 + r] = v>0.f ? v : 0.f;
}

// ---------------- tail: wL GEMM + rownorm + packE + Epp (R12 body, bit-frozen) ----------------
__global__ __launch_bounds__(256) void mlp_tail_kernel(
    const float* __restrict__ Xt,
    const float* __restrict__ wL, const float* __restrict__ bL,
    const float* __restrict__ pinv_w, const float* __restrict__ pinv_b,
    float* __restrict__ embed, unsigned short* __restrict__ packE,
    float* __restrict__ Epp){
  __shared__ float xrow[1024];
  __shared__ float erow[256];
  __shared__ float wsum[4];
  const int n = blockIdx.x, t = threadIdx.x;
  #pragma unroll
  for (int q=0;q<4;q++) xrow[q*256+t] = Xt[(size_t)(q*256+t)*256 + n];
  __syncthreads();
  float acc = 0.f;
  #pragma unroll 16
  for (int k=0;k<1024;k++) acc += xrow[k] * wL[(size_t)k*256 + t];
  acc += bL[t];
  const int lane = t & 63, wv = t >> 6;
  float v = acc*acc;
  #pragma unroll
  for (int o=32;o;o>>=1) v += __shfl_xor(v,o);
  if (lane==0) wsum[wv]=v;
  __syncthreads();
  const float total = wsum[0]+wsum[1]+wsum[2]+wsum[3];
  const float inv = 1.0f/(sqrtf(total)+1e-6f);
  const float y = acc*inv;
  embed[(size_t)n*256+t] = y;
  erow[t] = y;
  {
    unsigned short h = bf16_rne(y);
    unsigned short l = bf16_rne(y - bf16_tof(h));
    const int tt=t>>5, kk=t&31, g=kk>>3, e=kk&7, s=g^((n>>1)&3);
    unsigned short* d = packE + (size_t)tt*16384 + n*32 + s*8 + e;
    d[0] = h; d[8192] = l;
  }
  __syncthreads();
  float a8[8] = {0.f,0.f,0.f,0.f,0.f,0.f,0.f,0.f};
  #pragma unroll 8
  for (int k=0;k<256;k++){
    const float ev = erow[k];
    const float4 w0v = *(const float4*)&pinv_w[(size_t)k*2048 + t*8];
    const float4 w1v = *(const float4*)&pinv_w[(size_t)k*2048 + t*8 + 4];
    a8[0] += ev*w0v.x; a8[1] += ev*w0v.y; a8[2] += ev*w0v.z; a8[3] += ev*w0v.w;
    a8[4] += ev*w1v.x; a8[5] += ev*w1v.y; a8[6] += ev*w1v.z; a8[7] += ev*w1v.w;
  }
  #pragma unroll
  for (int j=0;j<8;j++) a8[j] += pinv_b[t*8+j];
  float4* dst = (float4*)(Epp + (size_t)n*2048 + t*8);
  dst[0] = (float4){a8[0],a8[1],a8[2],a8[3]};
  dst[1] = (float4){a8[4],a8[5],a8[6],a8[7]};
}

// ---------------- proj + rownorm fused (bit-frozen) ----------------
__global__ __launch_bounds__(512) void proj_norm_kernel(
    const float* __restrict__ A, const unsigned short* __restrict__ packW,
    const float* __restrict__ bias, float* __restrict__ Hn, int K){
  __shared__ char smem[40960];
  f32x4 acc[2][4];
  #pragma unroll
  for (int i=0;i<2;i++)
    #pragma unroll
    for (int j=0;j<4;j++) acc[i][j] = (f32x4){0.f,0.f,0.f,0.f};
  const int bm = blockIdx.x * 64;
  mk1_gemm(A + (size_t)bm*K, K, packW, K, smem, acc);
  __syncthreads();

  const int tid = threadIdx.x, lane = tid&63, wv = tid>>6;
  const int wr = wv>>2, wc = wv&3;
  float* ns = (float*)smem;
  #pragma unroll
  for (int j=0;j<4;j++){
    const int c = wc*64 + j*16 + (lane&15);
    const float bb = bias[c];
    #pragma unroll
    for (int i=0;i<2;i++)
      #pragma unroll
      for (int reg=0;reg<4;reg++) acc[i][j][reg] += bb;
  }
  #pragma unroll
  for (int i=0;i<2;i++)
    #pragma unroll
    for (int reg=0;reg<4;reg++){
      float p = acc[i][0][reg]*acc[i][0][reg] + acc[i][1][reg]*acc[i][1][reg]
              + acc[i][2][reg]*acc[i][2][reg] + acc[i][3][reg]*acc[i][3][reg];
      #pragma unroll
      for (int o=1;o<16;o<<=1) p += __shfl_xor(p, o);
      if ((lane&15)==0) ns[wc*64 + wr*32 + i*16 + (lane>>4)*4 + reg] = p;
    }
  __syncthreads();
  #pragma unroll
  for (int i=0;i<2;i++){
    const int rl = wr*32 + i*16 + (lane>>4)*4;
    #pragma unroll
    for (int reg=0;reg<4;reg++){
      const int r = rl + reg;
      const float tot = ns[0*64+r]+ns[1*64+r]+ns[2*64+r]+ns[3*64+r];
      const float inv = 1.0f/(sqrtf(tot)+1e-6f);
      const size_t grow = (size_t)(bm + r);
      #pragma unroll
      for (int j=0;j<4;j++){
        const int c = wc*64 + j*16 + (lane&15);
        Hn[grow*256 + c] = acc[i][j][reg]*inv;
      }
    }
  }
}

// ---------------- sim GEMM + softmax + gumbel-argmax + outputs + q_inv, fused (bit-frozen) ----------------
__global__ __launch_bounds__(512) void sim_sample_kernel(
    const float* __restrict__ Hn, const unsigned short* __restrict__ packE,
    const float* __restrict__ embed, const float* __restrict__ temp,
    float* __restrict__ probs, float* __restrict__ codef,
    float* __restrict__ quant, float* __restrict__ norms,
    const float* __restrict__ Epp, const float* __restrict__ pinv_b,
    float* __restrict__ q_inv,
    uint32_t kc0, uint32_t kc1, uint32_t kp0, uint32_t kp1){
  __shared__ char smem[40960];
  f32x4 acc[2][4];
  #pragma unroll
  for (int i=0;i<2;i++)
    #pragma unroll
    for (int j=0;j<4;j++) acc[i][j] = (f32x4){0.f,0.f,0.f,0.f};
  const int bm = blockIdx.x * 64;
  mk1_gemm(Hn + (size_t)bm*256, 256, packE, 256, smem, acc);
  __syncthreads();

  float* redf = (float*)smem;            // [4][64]
  int*   redi = (int*)(smem+1024);       // [4][64]
  float* smax = (float*)(smem+2048);     // [64]
  float* ssum = (float*)(smem+2304);     // [64]
  float* ssel = (float*)(smem+2560);     // [64]
  int*  scode = (int*)(smem+2816);       // [64]

  const int tid = threadIdx.x, lane = tid&63, wv = tid>>6;
  const int wr = wv>>2, wc = wv&3;
  const float tv = temp[0];
  const float alpha = 1.0f/(tv*tv);
  #pragma unroll
  for (int i=0;i<2;i++)
    #pragma unroll
    for (int j=0;j<4;j++)
      #pragma unroll
      for (int reg=0;reg<4;reg++){
        const float s = acc[i][j][reg];
        const float dist = -2.0f*(alpha-1.0f)*s - 2.0f*s;
        acc[i][j][reg] = -dist;
      }
  // row max
  #pragma unroll
  for (int i=0;i<2;i++)
    #pragma unroll
    for (int reg=0;reg<4;reg++){
      float m = fmaxf(fmaxf(acc[i][0][reg], acc[i][1][reg]),
                      fmaxf(acc[i][2][reg], acc[i][3][reg]));
      #pragma unroll
      for (int o=1;o<16;o<<=1) m = fmaxf(m, __shfl_xor(m, o));
      if ((lane&15)==0) redf[wc*64 + wr*32 + i*16 + (lane>>4)*4 + reg] = m;
    }
  __syncthreads();
  if (tid < 64)
    smax[tid] = fmaxf(fmaxf(redf[0*64+tid], redf[1*64+tid]), fmaxf(redf[2*64+tid], redf[3*64+tid]));
  __syncthreads();
  // exp-sum
  #pragma unroll
  for (int i=0;i<2;i++)
    #pragma unroll
    for (int reg=0;reg<4;reg++){
      const int r = wr*32 + i*16 + (lane>>4)*4 + reg;
      const float m = smax[r];
      float p = expf(acc[i][0][reg]-m) + expf(acc[i][1][reg]-m)
              + expf(acc[i][2][reg]-m) + expf(acc[i][3][reg]-m);
      #pragma unroll
      for (int o=1;o<16;o<<=1) p += __shfl_xor(p, o);
      if ((lane&15)==0) redf[wc*64 + r] = p;
    }
  __syncthreads();
  if (tid < 64){
    ssum[tid] = redf[0*64+tid]+redf[1*64+tid]+redf[2*64+tid]+redf[3*64+tid];
    const uint32_t pb = random_bits32(kp0,kp1,(uint32_t)(bm+tid), 16384u);
    const float pf = __uint_as_float((pb>>9) | 0x3f800000u) - 1.0f;
    ssel[tid] = (pf > 0.0f) ? 1.0f : 0.0f;
  }
  __syncthreads();
  // gumbel argmax (bit-frozen comparison order)
  #pragma unroll
  for (int i=0;i<2;i++)
    #pragma unroll
    for (int reg=0;reg<4;reg++){
      const int r = wr*32 + i*16 + (lane>>4)*4 + reg;
      const uint32_t grow = (uint32_t)(bm + r);
      float zb = -1e38f; int ib = 0x7fffffff;
      #pragma unroll
      for (int j=0;j<4;j++){
        const int c = wc*64 + j*16 + (lane&15);
        const uint32_t bits = random_bits32(kc0,kc1, grow*256u + (uint32_t)c, 4194304u);
        const float f = __uint_as_float((bits>>9) | 0x3f800000u) - 1.0f;
        const float TINY = 1.17549435082228751e-38f;
        const float u = fmaxf(TINY, f + TINY);
        const float g = -logf(-logf(u));
        const float z = acc[i][j][reg] + g;
        if (z > zb || (z == zb && c < ib)){ zb = z; ib = c; }
      }
      #pragma unroll
      for (int o=1;o<16;o<<=1){
        const float zo = __shfl_xor(zb, o); const int io = __shfl_xor(ib, o);
        if (zo > zb || (zo == zb && io < ib)){ zb = zo; ib = io; }
      }
      if ((lane&15)==0){ redf[wc*64 + r] = zb; redi[wc*64 + r] = ib; }
    }
  __syncthreads();
  if (tid < 64){
    float zb = redf[0*64+tid]; int ib = redi[0*64+tid];
    #pragma unroll
    for (int w=1; w<4; w++)
      if (redf[w*64+tid] > zb || (redf[w*64+tid] == zb && redi[w*64+tid] < ib)){
        zb = redf[w*64+tid]; ib = redi[w*64+tid];
      }
    scode[tid] = ib;
  }
  __syncthreads();
  // probs/quant + ||embed[code]-h|| partials
  #pragma unroll
  for (int i=0;i<2;i++)
    #pragma unroll
    for (int reg=0;reg<4;reg++){
      const int r = wr*32 + i*16 + (lane>>4)*4 + reg;
      const size_t grow = (size_t)(bm + r);
      const float m = smax[r], sum = ssum[r], sel = ssel[r];
      const int code = scode[r];
      float p2 = 0.f;
      #pragma unroll
      for (int j=0;j<4;j++){
        const int c = wc*64 + j*16 + (lane&15);
        const float e = expf(acc[i][j][reg] - m);
        probs[grow*256 + c] = (e/sum) * sel;
        const float ev = embed[(size_t)code*256 + c];
        quant[grow*256 + c] = ev * sel;
        const float d = ev - Hn[grow*256 + c];
        p2 += d*d;
      }
      #pragma unroll
      for (int o=1;o<16;o<<=1) p2 += __shfl_xor(p2, o);
      if ((lane&15)==0) redf[wc*64 + r] = p2;
    }
  __syncthreads();
  if (tid < 64){
    norms[bm+tid] = sqrtf(redf[0*64+tid]+redf[1*64+tid]+redf[2*64+tid]+redf[3*64+tid]);
    codef[bm+tid] = (float)scode[tid] * ssel[tid];
  }
  // q_inv rows: sel ? Epp[code] : pinv_b
  #pragma unroll
  for (int rr=0; rr<8; rr++){
    const int r = wv*8 + rr;
    const int code = scode[r];
    const float sel = ssel[r];
    const float4* s4 = (const float4*)((sel != 0.0f) ? (Epp + (size_t)code*2048) : pinv_b);
    float4* dst = (float4*)(q_inv + (size_t)(bm + r)*2048);
    #pragma unroll
    for (int q=0;q<8;q++) dst[q*64 + lane] = s4[q*64 + lane];
  }
}

// ---------------- vq_loss = mean(norms) ----------------
__global__ __launch_bounds__(256) void loss_kernel(const float* __restrict__ norms,
                                                   float* __restrict__ outp){
  const int t = threadIdx.x;
  float s = 0.f;
  for (int i=t;i<32768;i+=256) s += norms[i];
  #pragma unroll
  for (int o=32;o;o>>=1) s += __shfl_xor(s,o);
  __shared__ float wred[4];
  if ((t&63)==0) wred[t>>6]=s;
  __syncthreads();
  if (t==0) outp[0] = (wred[0]+wred[1]+wred[2]+wred[3]) * (1.0f/32768.0f);
}

// ---------------- launch ----------------
extern "C" void kernel_launch(void* const* d_in, const int* in_sizes, int n_in,
                              void* d_out, int out_size, void* d_ws, size_t ws_size,
                              hipStream_t stream){
  const float* h_in  = (const float*)d_in[0];
  const float* temp  = (const float*)d_in[1];
  const float* proj_w= (const float*)d_in[2];
  const float* proj_b= (const float*)d_in[3];
  const float* pinv_w= (const float*)d_in[4];
  const float* pinv_b= (const float*)d_in[5];
  const float* w0 = (const float*)d_in[6];
  const float* b0 = (const float*)d_in[7];
  const float* g0 = (const float*)d_in[8];
  const float* be0= (const float*)d_in[9];
  const float* wm = (const float*)d_in[10];
  const float* bm = (const float*)d_in[11];
  const float* gm = (const float*)d_in[12];
  const float* bem= (const float*)d_in[13];
  const float* wL = (const float*)d_in[14];
  const float* bL = (const float*)d_in[15];

  float* out = (float*)d_out;
  float* q_inv  = out;                  // [32768,2048]
  float* o_code = out + 67108864;       // [32768]
  float* o_quant= out + 67141632;       // [32768,256]
  float* o_probs= out + 75530240;       // [32768,256]
  float* o_loss = out + 83918848;       // [1]

  // scratch in d_ws
  float* ws = (float*)d_ws;
  float* Hn     = ws + 0;               // [32768,256]
  float* XtA    = ws + 8388608;         // [1024,256] transposed activations
  float* XtB    = ws + 8650752;         // [1024,256]
  float* embed  = ws + 8912896;         // [256,256]
  float* norms  = ws + 8978432;         // [32768]
  float* Epp    = ws + 9076736;         // [256,2048]
  unsigned short* packW = (unsigned short*)(ws + 9601024);   // 64 steps x 16384 shorts
  unsigned short* packE = (unsigned short*)(ws + 10125312);  // 8 steps x 16384 shorts

  uint32_t kc0,kc1,kp0,kp1;
#if PARTITIONABLE
  threefry2x32(0u,42u, 0u,0u, kc0,kc1);
  threefry2x32(0u,42u, 0u,1u, kp0,kp1);
#else
  { uint32_t a0,b0w,a1,b1w;
    threefry2x32(0u,42u, 0u,2u, a0,b0w);
    threefry2x32(0u,42u, 1u,3u, a1,b1w);
    kc0=a0; kc1=a1; kp0=b0w; kp1=b1w; }
#endif

  // pack proj_w + l0 (validated merged prep)
  prep_kernel<<<256,256,0,stream>>>(proj_w, packW, w0, b0, g0, be0, XtA);

  // big proj (depends only on packW)
  proj_norm_kernel<<<512,512,0,stream>>>(h_in, packW, proj_b, Hn, 2048);

  // codebook MLP mids: 1-col blocks, grid 1024 (max TLP along the measured gradient)
  mid1_kernel<<<1024,256,0,stream>>>(XtA, wm + 0*1048576, bm + 0*1024, gm + 0*1024, bem + 0*1024, XtB);
  mid1_kernel<<<1024,256,0,stream>>>(XtB, wm + 1*1048576, bm + 1*1024, gm + 1*1024, bem + 1*1024, XtA);
  mid1_kernel<<<1024,256,0,stream>>>(XtA, wm + 2*1048576, bm + 2*1024, gm + 2*1024, bem + 2*1024, XtB);
  mid1_kernel<<<1024,256,0,stream>>>(XtB, wm + 3*1048576, bm + 3*1024, gm + 3*1024, bem + 3*1024, XtA);
  mlp_tail_kernel<<<256,256,0,stream>>>(XtA, wL, bL, pinv_w, pinv_b, embed, packE, Epp);

  // sim + sample + all per-token outputs incl. q_inv
  sim_sample_kernel<<<512,512,0,stream>>>(Hn, packE, embed, temp,
                                          o_probs, o_code, o_quant, norms,
                                          Epp, pinv_b, q_inv,
                                          kc0,kc1,kp0,kp1);
  loss_kernel<<<1,256,0,stream>>>(norms, o_loss);
}

// Round 16
// 513.733 us; speedup vs baseline: 1.2656x; 1.1118x over previous
//
#include <hip/hip_runtime.h>
#include <hip/hip_bf16.h>
#include <stdint.h>
#include <stddef.h>

#ifndef PARTITIONABLE
#define PARTITIONABLE 1
#endif

typedef __attribute__((ext_vector_type(8))) short short8;
typedef __attribute__((ext_vector_type(4))) short short4v;
typedef __attribute__((ext_vector_type(4))) float f32x4;

// ---------------- threefry2x32 (exact JAX) ----------------
__host__ __device__ __forceinline__ uint32_t rotl32(uint32_t x, int d){ return (x<<d)|(x>>(32-d)); }

__host__ __device__ __forceinline__ void tf4(uint32_t&x0, uint32_t&x1, int r0,int r1,int r2,int r3){
  x0+=x1; x1=rotl32(x1,r0); x1^=x0;
  x0+=x1; x1=rotl32(x1,r1); x1^=x0;
  x0+=x1; x1=rotl32(x1,r2); x1^=x0;
  x0+=x1; x1=rotl32(x1,r3); x1^=x0;
}
__host__ __device__ __forceinline__ void threefry2x32(uint32_t k0,uint32_t k1,uint32_t x0,uint32_t x1,
                                                      uint32_t&y0,uint32_t&y1){
  uint32_t ks2 = k0^k1^0x1BD11BDAu;
  x0+=k0; x1+=k1;
  tf4(x0,x1,13,15,26,6);  x0+=k1;  x1+=ks2+1u;
  tf4(x0,x1,17,29,16,24); x0+=ks2; x1+=k0+2u;
  tf4(x0,x1,13,15,26,6);  x0+=k0;  x1+=k1+3u;
  tf4(x0,x1,17,29,16,24); x0+=k1;  x1+=ks2+4u;
  tf4(x0,x1,13,15,26,6);  x0+=ks2; x1+=k0+5u;
  y0=x0; y1=x1;
}

__device__ __forceinline__ uint32_t random_bits32(uint32_t k0,uint32_t k1,uint32_t idx, uint32_t half){
#if PARTITIONABLE
  uint32_t y0,y1; threefry2x32(k0,k1, 0u, idx, y0,y1);
  (void)half;
  return y0 ^ y1;
#else
  uint32_t y0,y1;
  if (idx < half) { threefry2x32(k0,k1, idx, idx+half, y0,y1); return y0; }
  else            { threefry2x32(k0,k1, idx-half, idx, y0,y1); return y1; }
#endif
}

// ---------------- bf16 split helpers ----------------
__device__ __forceinline__ unsigned short bf16_rne(float x){
  unsigned u = __float_as_uint(x);
  unsigned r = (u + 0x7FFFu + ((u>>16)&1u)) >> 16;
  return (unsigned short)r;
}
__device__ __forceinline__ float bf16_tof(unsigned short h){
  return __uint_as_float(((unsigned)h)<<16);
}
__device__ __forceinline__ void split8(const float* src, short8& hi, short8& lo){
  #pragma unroll
  for (int e=0;e<8;e++){
    unsigned short h = bf16_rne(src[e]);
    hi[e] = (short)h;
    lo[e] = (short)bf16_rne(src[e] - bf16_tof(h));
  }
}
__device__ __forceinline__ void split4(const float* src, short4v& hi, short4v& lo){
  #pragma unroll
  for (int e=0;e<4;e++){
    unsigned short h = bf16_rne(src[e]);
    hi[e] = (short)h;
    lo[e] = (short)bf16_rne(src[e] - bf16_tof(h));
  }
}

// ---------------- async global->LDS (16B/lane) ----------------
__device__ __forceinline__ void gll16(const void* g, void* l){
  __builtin_amdgcn_global_load_lds(
      (const __attribute__((address_space(1))) unsigned int*)g,
      (__attribute__((address_space(3))) unsigned int*)l, 16, 0, 0);
}

// ---------------- Markidis split-2 core (bit-frozen vs rounds 4-15) ----------------
__device__ __forceinline__ void mk1_gemm(const float* __restrict__ A, int lda,
                                         const unsigned short* __restrict__ packB,
                                         int K, char* smem, f32x4 (&acc)[2][4]){
  const int tid=threadIdx.x, lane=tid&63, wv=tid>>6;
  const int wr=wv>>2, wc=wv&3;
  const int arow=tid>>3, aseg=tid&7, swA=(arow>>1)&3;
  unsigned short* Ahi=(unsigned short*)smem;
  unsigned short* Alo=(unsigned short*)(smem+4096);
  unsigned short* Bhi=(unsigned short*)(smem+8192);
  unsigned short* Blo=(unsigned short*)(smem+24576);
  const int NT=K/32;
  const int sA = arow*32 + ((aseg>>1)^swA)*8 + (aseg&1)*4;
  const int seg = wv*2;

  float4 av = *(const float4*)(A + (size_t)arow*lda + aseg*4);
  for(int t=0;t<NT;t++){
    __syncthreads();
    {
      float af[4]={av.x,av.y,av.z,av.w}; short4v vh,vl; split4(af,vh,vl);
      *(short4v*)&Ahi[sA]=vh; *(short4v*)&Alo[sA]=vl;
      const unsigned short* src = packB + (size_t)t*16384;
      #pragma unroll
      for(int q=0;q<2;q++){
        gll16(src + (seg+q)*512 + lane*8,        (char*)Bhi + (seg+q)*1024);
        gll16(src + 8192 + (seg+q)*512 + lane*8, (char*)Blo + (seg+q)*1024);
      }
      if (t+1<NT) av = *(const float4*)(A + (size_t)arow*lda + (t+1)*32 + aseg*4);
    }
    __syncthreads();
    short8 ah[2],al[2],bh[4],bl[4];
    const int kg=lane>>4;
    #pragma unroll
    for(int i=0;i<2;i++){
      const int r = wr*32 + i*16 + (lane&15);
      const int offA = r*32 + ((kg ^ ((r>>1)&3))*8);
      ah[i]=*(const short8*)&Ahi[offA]; al[i]=*(const short8*)&Alo[offA];
    }
    #pragma unroll
    for(int j=0;j<4;j++){
      const int c = wc*64 + j*16 + (lane&15);
      const int offB = c*32 + ((kg ^ ((c>>1)&3))*8);
      bh[j]=*(const short8*)&Bhi[offB]; bl[j]=*(const short8*)&Blo[offB];
    }
    #pragma unroll
    for(int i=0;i<2;i++)
      #pragma unroll
      for(int j=0;j<4;j++){
        acc[i][j]=__builtin_amdgcn_mfma_f32_16x16x32_bf16(ah[i],bh[j],acc[i][j],0,0,0);
        acc[i][j]=__builtin_amdgcn_mfma_f32_16x16x32_bf16(ah[i],bl[j],acc[i][j],0,0,0);
        acc[i][j]=__builtin_amdgcn_mfma_f32_16x16x32_bf16(al[i],bh[j],acc[i][j],0,0,0);
      }
  }
}

// ---------------- BN(+ReLU) 4-col, transposed store (validated R9-R15) ----------------
__device__ __forceinline__ void bn_block_t(float (&acc)[4], int col0,
                                           const float* __restrict__ gma,
                                           const float* __restrict__ bta,
                                           float* __restrict__ Yt,
                                           float* Zs, float* red, float* mcol, float* vcol){
  const int r = threadIdx.x;
  #pragma unroll
  for (int j=0;j<4;j++) Zs[r*5+j] = acc[j];
  __syncthreads();
  if (r < 16){
    const int rl = r & 3, j = r >> 2;
    float s = 0.f;
    for (int rr=rl; rr<256; rr+=4) s += Zs[rr*5+j];
    red[rl*4+j] = s;
  }
  __syncthreads();
  if (r < 4)
    mcol[r] = (red[0*4+r]+red[1*4+r]+red[2*4+r]+red[3*4+r]) * (1.0f/256.0f);
  __syncthreads();
  if (r < 16){
    const int rl = r & 3, j = r >> 2;
    const float m = mcol[j];
    float s2 = 0.f;
    for (int rr=rl; rr<256; rr+=4){ float d = Zs[rr*5+j]-m; s2 += d*d; }
    red[rl*4+j] = s2;
  }
  __syncthreads();
  if (r < 4)
    vcol[r] = (red[0*4+r]+red[1*4+r]+red[2*4+r]+red[3*4+r]) * (1.0f/256.0f);
  __syncthreads();
  #pragma unroll
  for (int j=0;j<4;j++){
    const int c = col0 + j;
    const float scale = gma[c] * rsqrtf(vcol[j] + 1e-5f);
    const float sh = bta[c];
    const float v = (acc[j]-mcol[j])*scale + sh;
    Yt[(size_t)c*256 + r] = v > 0.f ? v : 0.f;
  }
}

// ---------------- prep: pack proj_w + l0 BN (validated R14/R15) ----------------
__global__ __launch_bounds__(256) void prep_kernel(
    const float* __restrict__ proj_w, unsigned short* __restrict__ packW,
    const float* __restrict__ w0, const float* __restrict__ b0,
    const float* __restrict__ g0, const float* __restrict__ be0,
    float* __restrict__ XtA){
  __shared__ float Zs[256*5];
  __shared__ float red[16], mcol[4], vcol[4];
  const int b = blockIdx.x, tid = threadIdx.x;
  {
    const int t = b>>2, s = b&3, c = tid;
    const int g = s ^ ((c>>1)&3);
    const float* p = proj_w + (size_t)(t*32 + g*8)*256 + c;
    float bf[8];
    #pragma unroll
    for(int e=0;e<8;e++) bf[e]=p[(size_t)e*256];
    short8 h,l; split8(bf,h,l);
    unsigned short* dst = packW + (size_t)t*16384 + c*32 + s*8;
    *(short8*)dst = h;
    *(short8*)(dst+8192) = l;
  }
  {
    const int col0 = b*4;
    float acc[4];
    #pragma unroll
    for (int j=0;j<4;j++) acc[j] = b0[col0+j];
    #pragma unroll
    for (int jj=0;jj<8;jj++){
      if ((tid >> (7-jj)) & 1){
        #pragma unroll
        for (int j=0;j<4;j++) acc[j] += w0[jj*1024 + col0 + j];
      }
    }
    bn_block_t(acc, col0, g0, be0, XtA, Zs, red, mcol, vcol);
  }
}

// ---------------- MLP mid layer: 2-col blocks, grid 512 (R12-proven optimum), unroll 32 ----------------
// Per-output accumulation (single acc, k ascending) and BN stripe order identical to R12.
__global__ __launch_bounds__(256) void mlp_layer2_kernel(
    const float* __restrict__ Xt, const float* __restrict__ W,
    const float* __restrict__ bias,
    const float* __restrict__ gma, const float* __restrict__ bta,
    float* __restrict__ Yt){
  __shared__ float Ws[1024*2];
  __shared__ float Zs[256*3];
  __shared__ float red[8], mcol[2], vcol[2];
  const int r = threadIdx.x;
  const int col0 = blockIdx.x*2;
  #pragma unroll
  for (int q=0;q<4;q++){
    const int k = q*256 + r;
    const float2 wv = *(const float2*)&W[(size_t)k*1024 + col0];
    *(float2*)&Ws[k*2] = wv;
  }
  __syncthreads();
  float acc0=0.f, acc1=0.f;
  #pragma unroll 32
  for (int k=0;k<1024;k++){
    const float a = Xt[(size_t)k*256 + r];
    acc0 += a*Ws[k*2];
    acc1 += a*Ws[k*2+1];
  }
  acc0 += bias[col0]; acc1 += bias[col0+1];
  // BN stats per column: exact stripe-order replica (R12)
  Zs[r*3+0]=acc0; Zs[r*3+1]=acc1;
  __syncthreads();
  if (r < 8){
    const int rl = r & 3, j = r >> 2;
    float s=0.f;
    for (int rr=rl; rr<256; rr+=4) s += Zs[rr*3+j];
    red[rl*2+j] = s;
  }
  __syncthreads();
  if (r < 2) mcol[r] = (red[0*2+r]+red[1*2+r]+red[2*2+r]+red[3*2+r])*(1.0f/256.0f);
  __syncthreads();
  if (r < 8){
    const int rl = r & 3, j = r >> 2;
    const float m = mcol[j];
    float s2=0.f;
    for (int rr=rl; rr<256; rr+=4){ float d = Zs[rr*3+j]-m; s2 += d*d; }
    red[rl*2+j] = s2;
  }
  __syncthreads();
  if (r < 2) vcol[r] = (red[0*2+r]+red[1*2+r]+red[2*2+r]+red[3*2+r])*(1.0f/256.0f);
  __syncthreads();
  {
    const float s0 = gma[col0] * rsqrtf(vcol[0] + 1e-5f);
    const float v0 = (acc0-mcol[0])*s0 + bta[col0];
    Yt[(size_t)col0*256 + r] = v0 > 0.f ? v0 : 0.f;
    const float s1 = gma[col0+1] * rsqrtf(vcol[1] + 1e-5f);
    const float v1 = (acc1-mcol[1])*s1 + bta[col0+1];
    Yt[(size_t)(col0+1)*256 + r] = v1 > 0.f ? v1 : 0.f;
  }
}

// ---------------- tail: wL GEMM + rownorm + packE + Epp (R12 body, bit-frozen) ----------------
__global__ __launch_bounds__(256) void mlp_tail_kernel(
    const float* __restrict__ Xt,
    const float* __restrict__ wL, const float* __restrict__ bL,
    const float* __restrict__ pinv_w, const float* __restrict__ pinv_b,
    float* __restrict__ embed, unsigned short* __restrict__ packE,
    float* __restrict__ Epp){
  __shared__ float xrow[1024];
  __shared__ float erow[256];
  __shared__ float wsum[4];
  const int n = blockIdx.x, t = threadIdx.x;
  #pragma unroll
  for (int q=0;q<4;q++) xrow[q*256+t] = Xt[(size_t)(q*256+t)*256 + n];
  __syncthreads();
  float acc = 0.f;
  #pragma unroll 16
  for (int k=0;k<1024;k++) acc += xrow[k] * wL[(size_t)k*256 + t];
  acc += bL[t];
  const int lane = t & 63, wv = t >> 6;
  float v = acc*acc;
  #pragma unroll
  for (int o=32;o;o>>=1) v += __shfl_xor(v,o);
  if (lane==0) wsum[wv]=v;
  __syncthreads();
  const float total = wsum[0]+wsum[1]+wsum[2]+wsum[3];
  const float inv = 1.0f/(sqrtf(total)+1e-6f);
  const float y = acc*inv;
  embed[(size_t)n*256+t] = y;
  erow[t] = y;
  {
    unsigned short h = bf16_rne(y);
    unsigned short l = bf16_rne(y - bf16_tof(h));
    const int tt=t>>5, kk=t&31, g=kk>>3, e=kk&7, s=g^((n>>1)&3);
    unsigned short* d = packE + (size_t)tt*16384 + n*32 + s*8 + e;
    d[0] = h; d[8192] = l;
  }
  __syncthreads();
  float a8[8] = {0.f,0.f,0.f,0.f,0.f,0.f,0.f,0.f};
  #pragma unroll 8
  for (int k=0;k<256;k++){
    const float ev = erow[k];
    const float4 w0v = *(const float4*)&pinv_w[(size_t)k*2048 + t*8];
    const float4 w1v = *(const float4*)&pinv_w[(size_t)k*2048 + t*8 + 4];
    a8[0] += ev*w0v.x; a8[1] += ev*w0v.y; a8[2] += ev*w0v.z; a8[3] += ev*w0v.w;
    a8[4] += ev*w1v.x; a8[5] += ev*w1v.y; a8[6] += ev*w1v.z; a8[7] += ev*w1v.w;
  }
  #pragma unroll
  for (int j=0;j<8;j++) a8[j] += pinv_b[t*8+j];
  float4* dst = (float4*)(Epp + (size_t)n*2048 + t*8);
  dst[0] = (float4){a8[0],a8[1],a8[2],a8[3]};
  dst[1] = (float4){a8[4],a8[5],a8[6],a8[7]};
}

// ---------------- proj + rownorm fused (bit-frozen) ----------------
__global__ __launch_bounds__(512) void proj_norm_kernel(
    const float* __restrict__ A, const unsigned short* __restrict__ packW,
    const float* __restrict__ bias, float* __restrict__ Hn, int K){
  __shared__ char smem[40960];
  f32x4 acc[2][4];
  #pragma unroll
  for (int i=0;i<2;i++)
    #pragma unroll
    for (int j=0;j<4;j++) acc[i][j] = (f32x4){0.f,0.f,0.f,0.f};
  const int bm = blockIdx.x * 64;
  mk1_gemm(A + (size_t)bm*K, K, packW, K, smem, acc);
  __syncthreads();

  const int tid = threadIdx.x, lane = tid&63, wv = tid>>6;
  const int wr = wv>>2, wc = wv&3;
  float* ns = (float*)smem;
  #pragma unroll
  for (int j=0;j<4;j++){
    const int c = wc*64 + j*16 + (lane&15);
    const float bb = bias[c];
    #pragma unroll
    for (int i=0;i<2;i++)
      #pragma unroll
      for (int reg=0;reg<4;reg++) acc[i][j][reg] += bb;
  }
  #pragma unroll
  for (int i=0;i<2;i++)
    #pragma unroll
    for (int reg=0;reg<4;reg++){
      float p = acc[i][0][reg]*acc[i][0][reg] + acc[i][1][reg]*acc[i][1][reg]
              + acc[i][2][reg]*acc[i][2][reg] + acc[i][3][reg]*acc[i][3][reg];
      #pragma unroll
      for (int o=1;o<16;o<<=1) p += __shfl_xor(p, o);
      if ((lane&15)==0) ns[wc*64 + wr*32 + i*16 + (lane>>4)*4 + reg] = p;
    }
  __syncthreads();
  #pragma unroll
  for (int i=0;i<2;i++){
    const int rl = wr*32 + i*16 + (lane>>4)*4;
    #pragma unroll
    for (int reg=0;reg<4;reg++){
      const int r = rl + reg;
      const float tot = ns[0*64+r]+ns[1*64+r]+ns[2*64+r]+ns[3*64+r];
      const float inv = 1.0f/(sqrtf(tot)+1e-6f);
      const size_t grow = (size_t)(bm + r);
      #pragma unroll
      for (int j=0;j<4;j++){
        const int c = wc*64 + j*16 + (lane&15);
        Hn[grow*256 + c] = acc[i][j][reg]*inv;
      }
    }
  }
}

// ---------------- sim GEMM + softmax + gumbel-argmax + outputs + q_inv, fused (bit-frozen) ----------------
__global__ __launch_bounds__(512) void sim_sample_kernel(
    const float* __restrict__ Hn, const unsigned short* __restrict__ packE,
    const float* __restrict__ embed, const float* __restrict__ temp,
    float* __restrict__ probs, float* __restrict__ codef,
    float* __restrict__ quant, float* __restrict__ norms,
    const float* __restrict__ Epp, const float* __restrict__ pinv_b,
    float* __restrict__ q_inv,
    uint32_t kc0, uint32_t kc1, uint32_t kp0, uint32_t kp1){
  __shared__ char smem[40960];
  f32x4 acc[2][4];
  #pragma unroll
  for (int i=0;i<2;i++)
    #pragma unroll
    for (int j=0;j<4;j++) acc[i][j] = (f32x4){0.f,0.f,0.f,0.f};
  const int bm = blockIdx.x * 64;
  mk1_gemm(Hn + (size_t)bm*256, 256, packE, 256, smem, acc);
  __syncthreads();

  float* redf = (float*)smem;            // [4][64]
  int*   redi = (int*)(smem+1024);       // [4][64]
  float* smax = (float*)(smem+2048);     // [64]
  float* ssum = (float*)(smem+2304);     // [64]
  float* ssel = (float*)(smem+2560);     // [64]
  int*  scode = (int*)(smem+2816);       // [64]

  const int tid = threadIdx.x, lane = tid&63, wv = tid>>6;
  const int wr = wv>>2, wc = wv&3;
  const float tv = temp[0];
  const float alpha = 1.0f/(tv*tv);
  #pragma unroll
  for (int i=0;i<2;i++)
    #pragma unroll
    for (int j=0;j<4;j++)
      #pragma unroll
      for (int reg=0;reg<4;reg++){
        const float s = acc[i][j][reg];
        const float dist = -2.0f*(alpha-1.0f)*s - 2.0f*s;
        acc[i][j][reg] = -dist;
      }
  // row max
  #pragma unroll
  for (int i=0;i<2;i++)
    #pragma unroll
    for (int reg=0;reg<4;reg++){
      float m = fmaxf(fmaxf(acc[i][0][reg], acc[i][1][reg]),
                      fmaxf(acc[i][2][reg], acc[i][3][reg]));
      #pragma unroll
      for (int o=1;o<16;o<<=1) m = fmaxf(m, __shfl_xor(m, o));
      if ((lane&15)==0) redf[wc*64 + wr*32 + i*16 + (lane>>4)*4 + reg] = m;
    }
  __syncthreads();
  if (tid < 64)
    smax[tid] = fmaxf(fmaxf(redf[0*64+tid], redf[1*64+tid]), fmaxf(redf[2*64+tid], redf[3*64+tid]));
  __syncthreads();
  // exp-sum
  #pragma unroll
  for (int i=0;i<2;i++)
    #pragma unroll
    for (int reg=0;reg<4;reg++){
      const int r = wr*32 + i*16 + (lane>>4)*4 + reg;
      const float m = smax[r];
      float p = expf(acc[i][0][reg]-m) + expf(acc[i][1][reg]-m)
              + expf(acc[i][2][reg]-m) + expf(acc[i][3][reg]-m);
      #pragma unroll
      for (int o=1;o<16;o<<=1) p += __shfl_xor(p, o);
      if ((lane&15)==0) redf[wc*64 + r] = p;
    }
  __syncthreads();
  if (tid < 64){
    ssum[tid] = redf[0*64+tid]+redf[1*64+tid]+redf[2*64+tid]+redf[3*64+tid];
    const uint32_t pb = random_bits32(kp0,kp1,(uint32_t)(bm+tid), 16384u);
    const float pf = __uint_as_float((pb>>9) | 0x3f800000u) - 1.0f;
    ssel[tid] = (pf > 0.0f) ? 1.0f : 0.0f;
  }
  __syncthreads();
  // gumbel argmax (bit-frozen comparison order)
  #pragma unroll
  for (int i=0;i<2;i++)
    #pragma unroll
    for (int reg=0;reg<4;reg++){
      const int r = wr*32 + i*16 + (lane>>4)*4 + reg;
      const uint32_t grow = (uint32_t)(bm + r);
      float zb = -1e38f; int ib = 0x7fffffff;
      #pragma unroll
      for (int j=0;j<4;j++){
        const int c = wc*64 + j*16 + (lane&15);
        const uint32_t bits = random_bits32(kc0,kc1, grow*256u + (uint32_t)c, 4194304u);
        const float f = __uint_as_float((bits>>9) | 0x3f800000u) - 1.0f;
        const float TINY = 1.17549435082228751e-38f;
        const float u = fmaxf(TINY, f + TINY);
        const float g = -logf(-logf(u));
        const float z = acc[i][j][reg] + g;
        if (z > zb || (z == zb && c < ib)){ zb = z; ib = c; }
      }
      #pragma unroll
      for (int o=1;o<16;o<<=1){
        const float zo = __shfl_xor(zb, o); const int io = __shfl_xor(ib, o);
        if (zo > zb || (zo == zb && io < ib)){ zb = zo; ib = io; }
      }
      if ((lane&15)==0){ redf[wc*64 + r] = zb; redi[wc*64 + r] = ib; }
    }
  __syncthreads();
  if (tid < 64){
    float zb = redf[0*64+tid]; int ib = redi[0*64+tid];
    #pragma unroll
    for (int w=1; w<4; w++)
      if (redf[w*64+tid] > zb || (redf[w*64+tid] == zb && redi[w*64+tid] < ib)){
        zb = redf[w*64+tid]; ib = redi[w*64+tid];
      }
    scode[tid] = ib;
  }
  __syncthreads();
  // probs/quant + ||embed[code]-h|| partials
  #pragma unroll
  for (int i=0;i<2;i++)
    #pragma unroll
    for (int reg=0;reg<4;reg++){
      const int r = wr*32 + i*16 + (lane>>4)*4 + reg;
      const size_t grow = (size_t)(bm + r);
      const float m = smax[r], sum = ssum[r], sel = ssel[r];
      const int code = scode[r];
      float p2 = 0.f;
      #pragma unroll
      for (int j=0;j<4;j++){
        const int c = wc*64 + j*16 + (lane&15);
        const float e = expf(acc[i][j][reg] - m);
        probs[grow*256 + c] = (e/sum) * sel;
        const float ev = embed[(size_t)code*256 + c];
        quant[grow*256 + c] = ev * sel;
        const float d = ev - Hn[grow*256 + c];
        p2 += d*d;
      }
      #pragma unroll
      for (int o=1;o<16;o<<=1) p2 += __shfl_xor(p2, o);
      if ((lane&15)==0) redf[wc*64 + r] = p2;
    }
  __syncthreads();
  if (tid < 64){
    norms[bm+tid] = sqrtf(redf[0*64+tid]+redf[1*64+tid]+redf[2*64+tid]+redf[3*64+tid]);
    codef[bm+tid] = (float)scode[tid] * ssel[tid];
  }
  // q_inv rows: sel ? Epp[code] : pinv_b
  #pragma unroll
  for (int rr=0; rr<8; rr++){
    const int r = wv*8 + rr;
    const int code = scode[r];
    const float sel = ssel[r];
    const float4* s4 = (const float4*)((sel != 0.0f) ? (Epp + (size_t)code*2048) : pinv_b);
    float4* dst = (float4*)(q_inv + (size_t)(bm + r)*2048);
    #pragma unroll
    for (int q=0;q<8;q++) dst[q*64 + lane] = s4[q*64 + lane];
  }
}

// ---------------- vq_loss = mean(norms) ----------------
__global__ __launch_bounds__(256) void loss_kernel(const float* __restrict__ norms,
                                                   float* __restrict__ outp){
  const int t = threadIdx.x;
  float s = 0.f;
  for (int i=t;i<32768;i+=256) s += norms[i];
  #pragma unroll
  for (int o=32;o;o>>=1) s += __shfl_xor(s,o);
  __shared__ float wred[4];
  if ((t&63)==0) wred[t>>6]=s;
  __syncthreads();
  if (t==0) outp[0] = (wred[0]+wred[1]+wred[2]+wred[3]) * (1.0f/32768.0f);
}

// ---------------- launch ----------------
extern "C" void kernel_launch(void* const* d_in, const int* in_sizes, int n_in,
                              void* d_out, int out_size, void* d_ws, size_t ws_size,
                              hipStream_t stream){
  const float* h_in  = (const float*)d_in[0];
  const float* temp  = (const float*)d_in[1];
  const float* proj_w= (const float*)d_in[2];
  const float* proj_b= (const float*)d_in[3];
  const float* pinv_w= (const float*)d_in[4];
  const float* pinv_b= (const float*)d_in[5];
  const float* w0 = (const float*)d_in[6];
  const float* b0 = (const float*)d_in[7];
  const float* g0 = (const float*)d_in[8];
  const float* be0= (const float*)d_in[9];
  const float* wm = (const float*)d_in[10];
  const float* bm = (const float*)d_in[11];
  const float* gm = (const float*)d_in[12];
  const float* bem= (const float*)d_in[13];
  const float* wL = (const float*)d_in[14];
  const float* bL = (const float*)d_in[15];

  float* out = (float*)d_out;
  float* q_inv  = out;                  // [32768,2048]
  float* o_code = out + 67108864;       // [32768]
  float* o_quant= out + 67141632;       // [32768,256]
  float* o_probs= out + 75530240;       // [32768,256]
  float* o_loss = out + 83918848;       // [1]

  // scratch in d_ws
  float* ws = (float*)d_ws;
  float* Hn     = ws + 0;               // [32768,256]
  float* XtA    = ws + 8388608;         // [1024,256] transposed activations
  float* XtB    = ws + 8650752;         // [1024,256]
  float* embed  = ws + 8912896;         // [256,256]
  float* norms  = ws + 8978432;         // [32768]
  float* Epp    = ws + 9076736;         // [256,2048]
  unsigned short* packW = (unsigned short*)(ws + 9601024);   // 64 steps x 16384 shorts
  unsigned short* packE = (unsigned short*)(ws + 10125312);  // 8 steps x 16384 shorts

  uint32_t kc0,kc1,kp0,kp1;
#if PARTITIONABLE
  threefry2x32(0u,42u, 0u,0u, kc0,kc1);
  threefry2x32(0u,42u, 0u,1u, kp0,kp1);
#else
  { uint32_t a0,b0w,a1,b1w;
    threefry2x32(0u,42u, 0u,2u, a0,b0w);
    threefry2x32(0u,42u, 1u,3u, a1,b1w);
    kc0=a0; kc1=a1; kp0=b0w; kp1=b1w; }
#endif

  // pack proj_w + l0 (validated merged prep)
  prep_kernel<<<256,256,0,stream>>>(proj_w, packW, w0, b0, g0, be0, XtA);

  // big proj (depends only on packW)
  proj_norm_kernel<<<512,512,0,stream>>>(h_in, packW, proj_b, Hn, 2048);

  // codebook MLP mids: 2-col blocks, grid 512 (R12-proven optimum)
  mlp_layer2_kernel<<<512,256,0,stream>>>(XtA, wm + 0*1048576, bm + 0*1024, gm + 0*1024, bem + 0*1024, XtB);
  mlp_layer2_kernel<<<512,256,0,stream>>>(XtB, wm + 1*1048576, bm + 1*1024, gm + 1*1024, bem + 1*1024, XtA);
  mlp_layer2_kernel<<<512,256,0,stream>>>(XtA, wm + 2*1048576, bm + 2*1024, gm + 2*1024, bem + 2*1024, XtB);
  mlp_layer2_kernel<<<512,256,0,stream>>>(XtB, wm + 3*1048576, bm + 3*1024, gm + 3*1024, bem + 3*1024, XtA);
  mlp_tail_kernel<<<256,256,0,stream>>>(XtA, wL, bL, pinv_w, pinv_b, embed, packE, Epp);

  // sim + sample + all per-token outputs incl. q_inv
  sim_sample_kernel<<<512,512,0,stream>>>(Hn, packE, embed, temp,
                                          o_probs, o_code, o_quant, norms,
                                          Epp, pinv_b, q_inv,
                                          kc0,kc1,kp0,kp1);
  loss_kernel<<<1,256,0,stream>>>(norms, o_loss);
}